// Round 6
// baseline (68.761 us; speedup 1.0000x reference)
//
#include <hip/hip_runtime.h>
#include <hip/hip_bf16.h>

// AFMAttentionLayer: s[b,i,j] = sum_d x[b,i,d]*x[b,j,d]*wsum[d] + bsum
// out = s / denom[b], denom[b] = sum_ij s[b,i,j] = sum_d S_d^2*wsum[d] + F*F*bsum.
//
// Wave-per-batch, no LDS tile: one 64-lane wave computes a full 64x64 Gram
// matrix via mfma_f32_32x32x16_bf16 (2x2 tiles x 8 k-steps). For a Gram matrix
// the A- and B-fragment per-lane layouts coincide (lane l <-> x-row l&31,
// k-chunk hi=l>>5), so one set of global float4 loads feeds both operands:
// B = bf16(x), A = bf16(x*wsum) derived in-register.
//
// DENOMINATOR MUST BE EXACT FP32 (round-5 lesson): it has catastrophic
// cancellation; bf16-numerator-derived denom fails (absmax 82). Computed here
// from a dedicated coalesced column-sum pass over the wave's own tile
// (L2/L3-hot re-read), closed form sum_d S_d^2*wsum[d] + 4096*bsum.
//
// Stores use C's symmetry to write the transpose with float4 stores.
// B=4096, F=64, D=128, H=4.

constexpr int F = 64;
constexpr int D = 128;

using bf16x8 = __attribute__((ext_vector_type(8))) short;   // 8 bf16 = 4 VGPRs
using f32x16 = __attribute__((ext_vector_type(16))) float;  // 32x32 C tile / lane

// pack two f32 -> u32 of 2 bf16 (RNE); compiler emits v_cvt_pk_bf16_f32
__device__ __forceinline__ unsigned pk2(float lo, float hi) {
    float2 f2; f2.x = lo; f2.y = hi;
    __hip_bfloat162 h = __float22bfloat162_rn(f2);
    union { __hip_bfloat162 h2; unsigned u; } cv; cv.h2 = h;
    return cv.u;
}

__global__ __launch_bounds__(256, 4) void afm_kernel(
    const float* __restrict__ x, const float* __restrict__ w,
    const float* __restrict__ bias, float* __restrict__ out)
{
    __shared__ float sW[D];   // wsum, shared by all 4 waves (512 B LDS)

    const int t     = threadIdx.x;
    const int lane  = t & 63;
    const int wv    = t >> 6;
    const int batch = blockIdx.x * 4 + wv;   // one wave per batch
    const int cl    = lane & 31;
    const int hi    = lane >> 5;

    if (t < D) sW[t] = w[t] + w[D + t] + w[2 * D + t] + w[3 * D + t];
    const float4 bv = *reinterpret_cast<const float4*>(bias);
    const float bsum = (bv.x + bv.y) + (bv.z + bv.w);
    __syncthreads();

    const float* xb = x + (size_t)batch * (F * D);

    // ---- exact fp32 denominator: column sums S_d, coalesced row-major pass ----
    // lane reads cols [4cl, 4cl+4) of rows {hi, hi+2, hi+4, ...} (32 rows)
    float4 c4 = {0.f, 0.f, 0.f, 0.f};
    const float* xs = xb + hi * D + 4 * cl;
    #pragma unroll
    for (int m = 0; m < 32; ++m) {
        const float4 v = *reinterpret_cast<const float4*>(xs + (size_t)m * 2 * D);
        c4.x += v.x; c4.y += v.y; c4.z += v.z; c4.w += v.w;
    }
    // fold the other row-parity (lane^32 holds same cols, other 32 rows)
    c4.x += __shfl_xor(c4.x, 32, 64);
    c4.y += __shfl_xor(c4.y, 32, 64);
    c4.z += __shfl_xor(c4.z, 32, 64);
    c4.w += __shfl_xor(c4.w, 32, 64);
    const float4 wq = *reinterpret_cast<const float4*>(&sW[4 * cl]);
    float dp = c4.x * c4.x * wq.x + c4.y * c4.y * wq.y
             + c4.z * c4.z * wq.z + c4.w * c4.w * wq.w;
    #pragma unroll
    for (int off = 32; off; off >>= 1) dp += __shfl_xor(dp, off, 64);
    // lanes cl and cl+32 both counted every column -> x0.5
    const float rden = 1.0f / (0.5f * dp + 4096.0f * bsum);
    const float bb   = bsum * rden;

    // ---- MFMA main loop: 2x2 tiles of 32x32, K=16 per step, 8 steps ----
    const float* xr0 = xb + (size_t)cl * D;   // rows 0..31
    const float* xr1 = xr0 + 32 * D;          // rows 32..63

    f32x16 a00 = {0,0,0,0,0,0,0,0,0,0,0,0,0,0,0,0};
    f32x16 a01 = {0,0,0,0,0,0,0,0,0,0,0,0,0,0,0,0};
    f32x16 a10 = {0,0,0,0,0,0,0,0,0,0,0,0,0,0,0,0};
    f32x16 a11 = {0,0,0,0,0,0,0,0,0,0,0,0,0,0,0,0};

    #pragma unroll
    for (int s = 0; s < 8; ++s) {
        const int k0 = s * 16 + hi * 8;   // this lane's 8-float k-chunk
        // wsum from LDS (uniform per half-wave -> broadcast reads)
        const float4 wl = *reinterpret_cast<const float4*>(&sW[k0]);
        const float4 wh = *reinterpret_cast<const float4*>(&sW[k0 + 4]);
        // x loads: lane-pairs (l, l+32) cover full 64B lines of each row
        const float4 xa = *reinterpret_cast<const float4*>(xr0 + k0);
        const float4 xv = *reinterpret_cast<const float4*>(xr0 + k0 + 4);
        const float4 xc = *reinterpret_cast<const float4*>(xr1 + k0);
        const float4 xd = *reinterpret_cast<const float4*>(xr1 + k0 + 4);

        union { uint4 u; bf16x8 v; } B0, B1, A0, A1;
        B0.u.x = pk2(xa.x, xa.y);               B0.u.y = pk2(xa.z, xa.w);
        B0.u.z = pk2(xv.x, xv.y);               B0.u.w = pk2(xv.z, xv.w);
        A0.u.x = pk2(xa.x * wl.x, xa.y * wl.y); A0.u.y = pk2(xa.z * wl.z, xa.w * wl.w);
        A0.u.z = pk2(xv.x * wh.x, xv.y * wh.y); A0.u.w = pk2(xv.z * wh.z, xv.w * wh.w);
        B1.u.x = pk2(xc.x, xc.y);               B1.u.y = pk2(xc.z, xc.w);
        B1.u.z = pk2(xd.x, xd.y);               B1.u.w = pk2(xd.z, xd.w);
        A1.u.x = pk2(xc.x * wl.x, xc.y * wl.y); A1.u.y = pk2(xc.z * wl.z, xc.w * wl.w);
        A1.u.z = pk2(xd.x * wh.x, xd.y * wh.y); A1.u.w = pk2(xd.z * wh.z, xd.w * wh.w);

        a00 = __builtin_amdgcn_mfma_f32_32x32x16_bf16(A0.v, B0.v, a00, 0, 0, 0);
        a01 = __builtin_amdgcn_mfma_f32_32x32x16_bf16(A0.v, B1.v, a01, 0, 0, 0);
        a10 = __builtin_amdgcn_mfma_f32_32x32x16_bf16(A1.v, B0.v, a10, 0, 0, 0);
        a11 = __builtin_amdgcn_mfma_f32_32x32x16_bf16(A1.v, B1.v, a11, 0, 0, 0);
    }

    // ---- store: C symmetric -> write transpose, float4 stores ----
    // C/D layout (32x32): col = lane&31, row = (reg&3) + 8*(reg>>2) + 4*hi
    float* ob  = out + (size_t)batch * (F * F);
    float* o00 = ob + (size_t)cl * F + 4 * hi;              // tile rows 0..31, cols 0..31
    float* o01 = ob + (size_t)(32 + cl) * F + 4 * hi;       // A0 x B1 -> out[32+cl][row]
    float* o10 = ob + (size_t)cl * F + 32 + 4 * hi;         // A1 x B0 -> out[cl][32+row]
    float* o11 = ob + (size_t)(32 + cl) * F + 32 + 4 * hi;  // A1 x B1
    #pragma unroll
    for (int q = 0; q < 4; ++q) {
        float4 o;
        o.x = fmaf(a00[4*q+0], rden, bb); o.y = fmaf(a00[4*q+1], rden, bb);
        o.z = fmaf(a00[4*q+2], rden, bb); o.w = fmaf(a00[4*q+3], rden, bb);
        *reinterpret_cast<float4*>(o00 + 8 * q) = o;
        o.x = fmaf(a01[4*q+0], rden, bb); o.y = fmaf(a01[4*q+1], rden, bb);
        o.z = fmaf(a01[4*q+2], rden, bb); o.w = fmaf(a01[4*q+3], rden, bb);
        *reinterpret_cast<float4*>(o01 + 8 * q) = o;
        o.x = fmaf(a10[4*q+0], rden, bb); o.y = fmaf(a10[4*q+1], rden, bb);
        o.z = fmaf(a10[4*q+2], rden, bb); o.w = fmaf(a10[4*q+3], rden, bb);
        *reinterpret_cast<float4*>(o10 + 8 * q) = o;
        o.x = fmaf(a11[4*q+0], rden, bb); o.y = fmaf(a11[4*q+1], rden, bb);
        o.z = fmaf(a11[4*q+2], rden, bb); o.w = fmaf(a11[4*q+3], rden, bb);
        *reinterpret_cast<float4*>(o11 + 8 * q) = o;
    }
}

extern "C" void kernel_launch(void* const* d_in, const int* in_sizes, int n_in,
                              void* d_out, int out_size, void* d_ws, size_t ws_size,
                              hipStream_t stream) {
    const float* x  = (const float*)d_in[0];   // [4096, 64, 128]
    const float* w  = (const float*)d_in[1];   // [4, 128]
    const float* b  = (const float*)d_in[2];   // [4]
    float* out      = (float*)d_out;           // [4096, 64, 64]

    afm_kernel<<<1024, 256, 0, stream>>>(x, w, b, out);  // 4 waves/block, 1 batch/wave
}

// Round 8
// 39.774 us; speedup vs baseline: 1.7288x; 1.7288x over previous
//
#include <hip/hip_runtime.h>
#include <hip/hip_bf16.h>

// AFMAttentionLayer: s[b,i,j] = sum_d x[b,i,d]*x[b,j,d]*wsum[d] + bsum
// out = s / denom[b];  denom[b] = sum_d S_d^2*wsum[d] + F*F*bsum (fp32 closed form —
// MUST stay exact fp32: bf16-derived denominators fail (round-5 lesson, absmax 82)).
// Numerator via bf16 MFMA, single LDS tile B = bf16(X); A-fragments derived
// in-register (unpack, scale by wsum, repack). Single __syncthreads per block.
// Epilogue: C symmetric -> store transpose with NON-TEMPORAL float4 stores so the
// 64 MB out stream doesn't evict x from the 256 MB L3 (x+out working set 192 MB;
// round-4/6 evidence: out allocation costs ~65 MB/replay of x refetch).
// NOTE: __builtin_nontemporal_store needs a clang vector type, not HIP float4.
// B=4096, F=64, D=128, H=4.

constexpr int F = 64;
constexpr int D = 128;

using bf16x8 = __attribute__((ext_vector_type(8))) short;  // 8 bf16 = 4 VGPRs
using f32x4  = __attribute__((ext_vector_type(4))) float;

// Chunked+swizzled LDS tile: chunk = d>>3 (16), row (64), 8 bf16 = 16 B units.
// byte addr = (((chunk<<6)+row)<<4) ^ ((chunk&7)<<4); bank slot16 = (row&7)^(chunk&7).
__device__ __forceinline__ int tile_addr(int chunk, int row) {
    return ((((chunk << 6) + row) << 4) ^ ((chunk & 7) << 4));
}

// pack two f32 -> u32 of 2 bf16 (RNE); compiler emits v_cvt_pk_bf16_f32
__device__ __forceinline__ unsigned pk2(float lo, float hi) {
    float2 f2; f2.x = lo; f2.y = hi;
    __hip_bfloat162 h = __float22bfloat162_rn(f2);
    union { __hip_bfloat162 h2; unsigned u; } cv; cv.h2 = h;
    return cv.u;
}
__device__ __forceinline__ float lo16f(unsigned u) { return __uint_as_float(u << 16); }
__device__ __forceinline__ float hi16f(unsigned u) { return __uint_as_float(u & 0xFFFF0000u); }

__global__ __launch_bounds__(256, 8) void afm_kernel(
    const float* __restrict__ x, const float* __restrict__ w,
    const float* __restrict__ bias, float* __restrict__ out)
{
    __shared__ short sB[F * D];        // bf16 X tile, swizzled (16 KB)
    __shared__ float sW[D];            // wsum
    __shared__ float sSp[4][D];        // per-wave column-sum partials (2 KB)

    const int t    = threadIdx.x;
    const int blk  = blockIdx.x;
    const int lane = t & 63;
    const int wv   = t >> 6;

    if (t < D) sW[t] = w[t] + w[D + t] + w[2 * D + t] + w[3 * D + t];
    const float bsum = bias[0] + bias[1] + bias[2] + bias[3];

    // ---- stage bf16(x[blk]) into LDS + per-wave column partial sums ----
    const float* xb = x + (size_t)blk * (F * D);
    const int col   = (4 * t) & 127;        // col quad owned by this thread
    const int chunk = col >> 3;
    const int ebyte = (col & 7) << 1;       // 0 or 8
    float c0 = 0.f, c1 = 0.f, c2 = 0.f, c3 = 0.f;
    char* sBc = reinterpret_cast<char*>(sB);

    #pragma unroll
    for (int k = 0; k < 8; ++k) {
        const int f   = k * 1024 + 4 * t;
        const int row = f >> 7;             // = 8k + (t>>5)
        const float4 v = *reinterpret_cast<const float4*>(xb + f);
        c0 += v.x; c1 += v.y; c2 += v.z; c3 += v.w;
        uint2 pb; pb.x = pk2(v.x, v.y); pb.y = pk2(v.z, v.w);
        *reinterpret_cast<uint2*>(sBc + tile_addr(chunk, row) + ebyte) = pb;
    }
    // fold lane^32 (same col quad, other 8 rows of this wave) -> per-wave partials
    c0 += __shfl_xor(c0, 32, 64); c1 += __shfl_xor(c1, 32, 64);
    c2 += __shfl_xor(c2, 32, 64); c3 += __shfl_xor(c3, 32, 64);
    if (lane < 32) {                        // col == 4*lane here
        float4 cs; cs.x = c0; cs.y = c1; cs.z = c2; cs.w = c3;
        *reinterpret_cast<float4*>(&sSp[wv][col]) = cs;
    }
    __syncthreads();   // the ONLY barrier: tile + sW + sSp all visible

    // ---- per-wave denominator (redundant per wave; overlaps MFMA scheduling) ----
    const float S0 = sSp[0][lane] + sSp[1][lane] + sSp[2][lane] + sSp[3][lane];
    const float S1 = sSp[0][64 + lane] + sSp[1][64 + lane] + sSp[2][64 + lane] + sSp[3][64 + lane];
    float p = S0 * S0 * sW[lane] + S1 * S1 * sW[64 + lane];
    #pragma unroll
    for (int off = 32; off; off >>= 1) p += __shfl_xor(p, off, 64);

    // ---- MFMA: wave wv computes rows [wv*16, wv*16+16) x all 64 cols ----
    f32x4 acc[4] = {{0,0,0,0},{0,0,0,0},{0,0,0,0},{0,0,0,0}};
    const int fr   = lane & 15;
    const int kgrp = lane >> 4;
    const int r_a  = wv * 16 + fr;

    #pragma unroll
    for (int s = 0; s < 4; ++s) {           // K = 32 per step
        const int ch = 4 * s + kgrp;
        // A fragment: read own bf16 row, unpack -> scale by wsum -> repack
        const uint4  raw = *reinterpret_cast<const uint4*>(sBc + tile_addr(ch, r_a));
        const float4 wa  = *reinterpret_cast<const float4*>(&sW[ch * 8]);
        const float4 wb  = *reinterpret_cast<const float4*>(&sW[ch * 8 + 4]);
        union { uint4 u; bf16x8 v; } af;
        af.u.x = pk2(lo16f(raw.x) * wa.x, hi16f(raw.x) * wa.y);
        af.u.y = pk2(lo16f(raw.y) * wa.z, hi16f(raw.y) * wa.w);
        af.u.z = pk2(lo16f(raw.z) * wb.x, hi16f(raw.z) * wb.y);
        af.u.w = pk2(lo16f(raw.w) * wb.z, hi16f(raw.w) * wb.w);
        #pragma unroll
        for (int tj = 0; tj < 4; ++tj) {
            union { uint4 u; bf16x8 v; } bf;
            bf.u = *reinterpret_cast<const uint4*>(sBc + tile_addr(ch, tj * 16 + fr));
            acc[tj] = __builtin_amdgcn_mfma_f32_16x16x32_bf16(af.v, bf.v, acc[tj], 0, 0, 0);
        }
    }

    // ---- epilogue: C symmetric -> store transpose with NON-TEMPORAL float4 stores ----
    const float rden  = 1.0f / (p + 4096.0f * bsum);
    const int   rbase = wv * 16 + 4 * kgrp;      // contiguous in transposed layout
    float* ob = out + (size_t)blk * (F * F);
    #pragma unroll
    for (int tj = 0; tj < 4; ++tj) {
        f32x4 o;
        o.x = (acc[tj][0] + bsum) * rden;
        o.y = (acc[tj][1] + bsum) * rden;
        o.z = (acc[tj][2] + bsum) * rden;
        o.w = (acc[tj][3] + bsum) * rden;
        __builtin_nontemporal_store(o,
            reinterpret_cast<f32x4*>(ob + (size_t)(tj * 16 + fr) * F + rbase));
    }
}

extern "C" void kernel_launch(void* const* d_in, const int* in_sizes, int n_in,
                              void* d_out, int out_size, void* d_ws, size_t ws_size,
                              hipStream_t stream) {
    const float* x  = (const float*)d_in[0];   // [4096, 64, 128]
    const float* w  = (const float*)d_in[1];   // [4, 128]
    const float* b  = (const float*)d_in[2];   // [4]
    float* out      = (float*)d_out;           // [4096, 64, 64]

    afm_kernel<<<4096, 256, 0, stream>>>(x, w, b, out);
}

// Round 9
// 37.000 us; speedup vs baseline: 1.8584x; 1.0750x over previous
//
#include <hip/hip_runtime.h>
#include <hip/hip_bf16.h>

// AFMAttentionLayer: s[b,i,j] = sum_d x[b,i,d]*x[b,j,d]*wsum[d] + bsum
// out = s / denom[b];  denom[b] = sum_d S_d^2*wsum[d] + F*F*bsum (exact fp32 —
// bf16-derived denominators fail: round-5, absmax 82).
//
// Round-9: async staging. fp32 x-tile staged via global_load_lds (16B, zero VGPR
// round-trip -> full MLP, all 8KB/wave in flight). DMA writes LDS linearly, so
// the GLOBAL source column is pre-swizzled per lane (m173 pattern); reads use
// phys = row*512 + (colByte ^ ((row&7)<<4))  -> 2-way (free) LDS conflicts.
// bf16 conversion happens in the MFMA loop (VALU is ~85% idle). Colsums for the
// exact denominator are read back from the fp32 LDS tile. Plain stores (nt
// regressed, round 8). B=4096, F=64, D=128, H=4.

constexpr int F = 64;
constexpr int D = 128;

using bf16x8 = __attribute__((ext_vector_type(8))) short;  // 8 bf16 = 4 VGPRs
using f32x4  = __attribute__((ext_vector_type(4))) float;

// pack two f32 -> u32 of 2 bf16 (RNE); compiler emits v_cvt_pk_bf16_f32
__device__ __forceinline__ unsigned pk2(float lo, float hi) {
    float2 f2; f2.x = lo; f2.y = hi;
    __hip_bfloat162 h = __float22bfloat162_rn(f2);
    union { __hip_bfloat162 h2; unsigned u; } cv; cv.h2 = h;
    return cv.u;
}

__global__ __launch_bounds__(256, 4) void afm_kernel(
    const float* __restrict__ x, const float* __restrict__ w,
    const float* __restrict__ bias, float* __restrict__ out)
{
    __shared__ float sX[F * D];        // fp32 x tile, column-swizzled (32 KB)
    __shared__ float sW[D];            // wsum (512 B)
    __shared__ float sSp[8][D];        // per-(wave,half) colsum partials (4 KB)

    const int t      = threadIdx.x;
    const int blk    = blockIdx.x;
    const int lane   = t & 63;
    const int wv     = t >> 6;
    const int l31    = lane & 31;
    const int rowpar = t >> 5;         // 0..7 == (2*wv + hi) == row & 7 for this lane

    if (t < D) sW[t] = w[t] + w[D + t] + w[2 * D + t] + w[3 * D + t];
    const float bsum = bias[0] + bias[1] + bias[2] + bias[3];

    // ---- async stage: instr k of wave wv fills LDS [(k*4+wv)*1KB, +1KB) linearly.
    // lane writes phys slot lane*16; source col pre-swizzled so that
    // LDS[row*512 + (colByte ^ ((row&7)<<4))] == x[row][colByte/4 ..].
    const float* xb = x + (size_t)blk * (F * D);
    const int cb = l31 ^ rowpar;                     // this lane's 16B col-block
    const float* srcbase = xb + rowpar * D + cb * 4; // row rowpar (k=0)
    #pragma unroll
    for (int k = 0; k < 8; ++k) {
        const float* src = srcbase + k * 8 * D;      // row 8k+rowpar
        float* dst = sX + (k * 4 + wv) * 256;        // wave-uniform base
        __builtin_amdgcn_global_load_lds(
            (const __attribute__((address_space(1))) void*)src,
            (__attribute__((address_space(3))) void*)dst,
            16, 0, 0);
    }
    __syncthreads();   // drains vmcnt; tile + sW visible

    // ---- colsum partials from LDS (lane reads back its own staged slots) ----
    float4 c4 = {0.f, 0.f, 0.f, 0.f};
    #pragma unroll
    for (int k = 0; k < 8; ++k) {
        const float4 v = *reinterpret_cast<const float4*>(sX + (k * 4 + wv) * 256 + lane * 4);
        c4.x += v.x; c4.y += v.y; c4.z += v.z; c4.w += v.w;
    }
    *reinterpret_cast<float4*>(&sSp[rowpar][4 * cb]) = c4;   // unique slot per thread
    __syncthreads();

    // ---- exact fp32 denominator (per-wave redundant) ----
    float S0 = 0.f, S1 = 0.f;
    #pragma unroll
    for (int p8 = 0; p8 < 8; ++p8) { S0 += sSp[p8][lane]; S1 += sSp[p8][64 + lane]; }
    float dp = S0 * S0 * sW[lane] + S1 * S1 * sW[64 + lane];
    #pragma unroll
    for (int off = 32; off; off >>= 1) dp += __shfl_xor(dp, off, 64);
    const float rden = 1.0f / (dp + 4096.0f * bsum);

    // ---- MFMA: wave wv computes rows [wv*16, wv*16+16) x all 64 cols ----
    f32x4 acc[4] = {{0,0,0,0},{0,0,0,0},{0,0,0,0},{0,0,0,0}};
    const int fr   = lane & 15;
    const int kgrp = lane >> 4;
    const int r_a  = wv * 16 + fr;
    const char* sXc = reinterpret_cast<const char*>(sX);
    const int rowA = r_a * 512;
    const int swA  = (r_a & 7) << 4;
    const int swB  = (fr & 7) << 4;    // (tj*16+fr)&7 == fr&7 for all tj

    #pragma unroll
    for (int s = 0; s < 4; ++s) {      // K = 32 per step
        const int ch    = 4 * s + kgrp;
        const int cbyte = ch * 32;
        const int aA = rowA + (cbyte ^ swA);
        const float4 a0 = *reinterpret_cast<const float4*>(sXc + aA);
        const float4 a1 = *reinterpret_cast<const float4*>(sXc + (aA ^ 16));
        const float4 wa = *reinterpret_cast<const float4*>(&sW[ch * 8]);
        const float4 wb = *reinterpret_cast<const float4*>(&sW[ch * 8 + 4]);
        union { uint4 u; bf16x8 v; } af;
        af.u.x = pk2(a0.x * wa.x, a0.y * wa.y);
        af.u.y = pk2(a0.z * wa.z, a0.w * wa.w);
        af.u.z = pk2(a1.x * wb.x, a1.y * wb.y);
        af.u.w = pk2(a1.z * wb.z, a1.w * wb.w);
        #pragma unroll
        for (int tj = 0; tj < 4; ++tj) {
            const int aB = (tj * 16 + fr) * 512 + (cbyte ^ swB);
            const float4 b0 = *reinterpret_cast<const float4*>(sXc + aB);
            const float4 b1 = *reinterpret_cast<const float4*>(sXc + (aB ^ 16));
            union { uint4 u; bf16x8 v; } bf;
            bf.u.x = pk2(b0.x, b0.y); bf.u.y = pk2(b0.z, b0.w);
            bf.u.z = pk2(b1.x, b1.y); bf.u.w = pk2(b1.z, b1.w);
            acc[tj] = __builtin_amdgcn_mfma_f32_16x16x32_bf16(af.v, bf.v, acc[tj], 0, 0, 0);
        }
    }

    // ---- epilogue: C symmetric -> store transpose with float4 stores ----
    const int rbase = wv * 16 + 4 * kgrp;   // contiguous in transposed layout
    float* ob = out + (size_t)blk * (F * F);
    #pragma unroll
    for (int tj = 0; tj < 4; ++tj) {
        float4 o;
        o.x = (acc[tj][0] + bsum) * rden;
        o.y = (acc[tj][1] + bsum) * rden;
        o.z = (acc[tj][2] + bsum) * rden;
        o.w = (acc[tj][3] + bsum) * rden;
        *reinterpret_cast<float4*>(ob + (size_t)(tj * 16 + fr) * F + rbase) = o;
    }
}

extern "C" void kernel_launch(void* const* d_in, const int* in_sizes, int n_in,
                              void* d_out, int out_size, void* d_ws, size_t ws_size,
                              hipStream_t stream) {
    const float* x  = (const float*)d_in[0];   // [4096, 64, 128]
    const float* w  = (const float*)d_in[1];   // [4, 128]
    const float* b  = (const float*)d_in[2];   // [4]
    float* out      = (float*)d_out;           // [4096, 64, 64]

    afm_kernel<<<4096, 256, 0, stream>>>(x, w, b, out);
}

// Round 10
// 36.545 us; speedup vs baseline: 1.8815x; 1.0124x over previous
//
#include <hip/hip_runtime.h>
#include <hip/hip_bf16.h>

// AFMAttentionLayer: s[b,i,j] = sum_d x[b,i,d]*x[b,j,d]*wsum[d] + bsum
// out = s / denom[b];  denom[b] = sum_d S_d^2*wsum[d] + F*F*bsum (exact fp32 —
// bf16-derived denominators fail: round-5, absmax 82).
//
// Round-10: batch software pipeline. Grid 1024, 4 consecutive batches per block
// (exactly 4 blocks/CU resident -> zero block turnover). Double-buffered bf16
// tile + colsum partials; ONE barrier per batch. Batch m+1's 8 float4 global
// loads are issued at the top of iteration m (T14 issue-early/consume-late):
// their ~900cy HBM latency hides under m's pack+denom+MFMA+stores.
// Numerator via bf16 MFMA (single tile, A-fragments derived in-register);
// epilogue uses C's symmetry to store the transpose with float4 stores.
// B=4096, F=64, D=128, H=4.

constexpr int F = 64;
constexpr int D = 128;

using bf16x8 = __attribute__((ext_vector_type(8))) short;  // 8 bf16 = 4 VGPRs
using f32x4  = __attribute__((ext_vector_type(4))) float;

// Chunked+swizzled LDS tile: chunk = d>>3 (16), row (64), 8 bf16 = 16 B units.
// byte addr = (((chunk<<6)+row)<<4) ^ ((chunk&7)<<4); bank slot16 = (row&7)^(chunk&7).
__device__ __forceinline__ int tile_addr(int chunk, int row) {
    return ((((chunk << 6) + row) << 4) ^ ((chunk & 7) << 4));
}

// pack two f32 -> u32 of 2 bf16 (RNE); compiler emits v_cvt_pk_bf16_f32
__device__ __forceinline__ unsigned pk2(float lo, float hi) {
    float2 f2; f2.x = lo; f2.y = hi;
    __hip_bfloat162 h = __float22bfloat162_rn(f2);
    union { __hip_bfloat162 h2; unsigned u; } cv; cv.h2 = h;
    return cv.u;
}
__device__ __forceinline__ float lo16f(unsigned u) { return __uint_as_float(u << 16); }
__device__ __forceinline__ float hi16f(unsigned u) { return __uint_as_float(u & 0xFFFF0000u); }

__global__ __launch_bounds__(256, 4) void afm_kernel(
    const float* __restrict__ x, const float* __restrict__ w,
    const float* __restrict__ bias, float* __restrict__ out)
{
    __shared__ short sB[2][F * D];     // double-buffered bf16 X tile (2 x 16 KB)
    __shared__ float sW[D];            // wsum (512 B)
    __shared__ float sSp[2][4][D];     // double-buffered per-wave colsum partials (4 KB)

    const int t    = threadIdx.x;
    const int lane = t & 63;
    const int wv   = t >> 6;

    if (t < D) sW[t] = w[t] + w[D + t] + w[2 * D + t] + w[3 * D + t];
    const float bsum = bias[0] + bias[1] + bias[2] + bias[3];

    const int col   = (4 * t) & 127;        // col quad owned by this thread
    const int chunk = col >> 3;
    const int ebyte = (col & 7) << 1;       // 0 or 8
    const int fr    = lane & 15;
    const int kgrp  = lane >> 4;
    const int r_a   = wv * 16 + fr;
    const int rbase = wv * 16 + 4 * kgrp;

    const size_t b0 = (size_t)blockIdx.x * 4;      // first batch of this block
    const float* xb = x + b0 * (F * D);

    // ---- prologue: load batch 0 into registers ----
    float4 v[8];
    #pragma unroll
    for (int k = 0; k < 8; ++k)
        v[k] = *reinterpret_cast<const float4*>(xb + k * 1024 + 4 * t);

    #pragma unroll
    for (int m = 0; m < 4; ++m) {
        char* sBc = reinterpret_cast<char*>(&sB[m & 1][0]);

        // 1. issue next batch's loads (in flight across this whole iteration)
        float4 vn[8];
        if (m < 3) {
            const float* xn = xb + (size_t)(m + 1) * (F * D);
            #pragma unroll
            for (int k = 0; k < 8; ++k)
                vn[k] = *reinterpret_cast<const float4*>(xn + k * 1024 + 4 * t);
        }

        // 2. pack current batch -> LDS tile; accumulate column sums from regs
        float c0 = 0.f, c1 = 0.f, c2 = 0.f, c3 = 0.f;
        #pragma unroll
        for (int k = 0; k < 8; ++k) {
            const int row = 8 * k + (t >> 5);
            c0 += v[k].x; c1 += v[k].y; c2 += v[k].z; c3 += v[k].w;
            uint2 pb; pb.x = pk2(v[k].x, v[k].y); pb.y = pk2(v[k].z, v[k].w);
            *reinterpret_cast<uint2*>(sBc + tile_addr(chunk, row) + ebyte) = pb;
        }
        c0 += __shfl_xor(c0, 32, 64); c1 += __shfl_xor(c1, 32, 64);
        c2 += __shfl_xor(c2, 32, 64); c3 += __shfl_xor(c3, 32, 64);
        if (lane < 32) {
            float4 cs; cs.x = c0; cs.y = c1; cs.z = c2; cs.w = c3;
            *reinterpret_cast<float4*>(&sSp[m & 1][wv][col]) = cs;
        }
        __syncthreads();   // one barrier per batch (dbuf makes it sufficient)

        // 3. exact fp32 denominator (per-wave redundant)
        const float S0 = sSp[m & 1][0][lane] + sSp[m & 1][1][lane]
                       + sSp[m & 1][2][lane] + sSp[m & 1][3][lane];
        const float S1 = sSp[m & 1][0][64 + lane] + sSp[m & 1][1][64 + lane]
                       + sSp[m & 1][2][64 + lane] + sSp[m & 1][3][64 + lane];
        float p = S0 * S0 * sW[lane] + S1 * S1 * sW[64 + lane];
        #pragma unroll
        for (int off = 32; off; off >>= 1) p += __shfl_xor(p, off, 64);
        const float rden = 1.0f / (p + 4096.0f * bsum);

        // 4. MFMA: wave wv computes rows [wv*16, wv*16+16) x all 64 cols
        f32x4 acc[4] = {{0,0,0,0},{0,0,0,0},{0,0,0,0},{0,0,0,0}};
        #pragma unroll
        for (int s = 0; s < 4; ++s) {       // K = 32 per step
            const int ch = 4 * s + kgrp;
            const uint4  raw = *reinterpret_cast<const uint4*>(sBc + tile_addr(ch, r_a));
            const float4 wa  = *reinterpret_cast<const float4*>(&sW[ch * 8]);
            const float4 wb  = *reinterpret_cast<const float4*>(&sW[ch * 8 + 4]);
            union { uint4 u; bf16x8 vv; } af;
            af.u.x = pk2(lo16f(raw.x) * wa.x, hi16f(raw.x) * wa.y);
            af.u.y = pk2(lo16f(raw.y) * wa.z, hi16f(raw.y) * wa.w);
            af.u.z = pk2(lo16f(raw.z) * wb.x, hi16f(raw.z) * wb.y);
            af.u.w = pk2(lo16f(raw.w) * wb.z, hi16f(raw.w) * wb.w);
            #pragma unroll
            for (int tj = 0; tj < 4; ++tj) {
                union { uint4 u; bf16x8 vv; } bf;
                bf.u = *reinterpret_cast<const uint4*>(sBc + tile_addr(ch, tj * 16 + fr));
                acc[tj] = __builtin_amdgcn_mfma_f32_16x16x32_bf16(af.vv, bf.vv, acc[tj], 0, 0, 0);
            }
        }

        // 5. epilogue: C symmetric -> store transpose with float4 stores
        float* ob = out + (b0 + m) * (size_t)(F * F);
        #pragma unroll
        for (int tj = 0; tj < 4; ++tj) {
            float4 o;
            o.x = (acc[tj][0] + bsum) * rden;
            o.y = (acc[tj][1] + bsum) * rden;
            o.z = (acc[tj][2] + bsum) * rden;
            o.w = (acc[tj][3] + bsum) * rden;
            *reinterpret_cast<float4*>(ob + (size_t)(tj * 16 + fr) * F + rbase) = o;
        }

        // 6. rotate prefetched registers
        if (m < 3) {
            #pragma unroll
            for (int k = 0; k < 8; ++k) v[k] = vn[k];
        }
    }
}

extern "C" void kernel_launch(void* const* d_in, const int* in_sizes, int n_in,
                              void* d_out, int out_size, void* d_ws, size_t ws_size,
                              hipStream_t stream) {
    const float* x  = (const float*)d_in[0];   // [4096, 64, 128]
    const float* w  = (const float*)d_in[1];   // [4, 128]
    const float* b  = (const float*)d_in[2];   // [4]
    float* out      = (float*)d_out;           // [4096, 64, 64]

    afm_kernel<<<1024, 256, 0, stream>>>(x, w, b, out);  // 4 batches per block
}